// Round 7
// baseline (86.261 us; speedup 1.0000x reference)
//
#include <hip/hip_runtime.h>
#include <math.h>

typedef unsigned short u16;
typedef __attribute__((ext_vector_type(8))) short bf16x8;
typedef __attribute__((ext_vector_type(4))) float f32x4;

#define D_EMB 1152
#define NFR 4096
#define SQRT_D 33.94112549695428f

__device__ __forceinline__ u16 f2bf(float f) {
  unsigned u = __float_as_uint(f);
  u = (u + 0x7FFFu + ((u >> 16) & 1u)) >> 16;
  return (u16)u;
}
__device__ __forceinline__ float bf2f(u16 h) { return __uint_as_float(((unsigned)h) << 16); }

// ================= k_prep: [0,512) local-fusion | [512,528) text norm | [528,656) transpose =================
__global__ __launch_bounds__(256) void k_prep(const float* __restrict__ fe,
                                              const float* __restrict__ text,
                                              u16* __restrict__ loc_n,
                                              u16* __restrict__ nf,
                                              u16* __restrict__ te_n,
                                              u16* __restrict__ nfT,
                                              float* __restrict__ invr,
                                              float* __restrict__ kpart,
                                              const float* __restrict__ tau_lp) {
  __shared__ __align__(16) float clip[8][1160];
  __shared__ float norms[8];
  __shared__ float sc[8][8];
  __shared__ float nrm2[8];
  __shared__ float wsum2[4];
  __shared__ float tile[32][33];
  __shared__ float cred[8][32];
  __shared__ float tinv[32];
  const int t = threadIdx.x;

  if (blockIdx.x >= 528) {  // ---------- transpose + frame norms + colsum partials ----------
    const int b2 = blockIdx.x - 528;
    const int k0b = b2 * 32;
    {  // phase 1: row norms (8 threads per row)
      int r = t >> 3, s = t & 7;
      const float4* row = (const float4*)(fe + (size_t)(k0b + r) * D_EMB);
      float ss = 0.f;
      for (int k = s; k < 288; k += 8) {
        float4 v = row[k];
        ss += v.x * v.x + v.y * v.y + v.z * v.z + v.w * v.w;
      }
      ss += __shfl_xor(ss, 1);
      ss += __shfl_xor(ss, 2);
      ss += __shfl_xor(ss, 4);
      if (s == 0) {
        float iv = 1.f / (sqrtf(ss) + 1e-6f);
        tinv[r] = iv;
        invr[k0b + r] = iv;
      }
    }
    __syncthreads();
    const int tx = t & 31, ty = t >> 5;
    for (int d0 = 0; d0 < D_EMB; d0 += 32) {
      float csum = 0.f;
#pragma unroll
      for (int s4 = 0; s4 < 4; ++s4) {
        float v = fe[(size_t)(k0b + ty + 8 * s4) * D_EMB + d0 + tx];
        tile[ty + 8 * s4][tx] = v;
        csum += v;
      }
      cred[ty][tx] = csum;
      __syncthreads();
      const float iv = tinv[tx];
#pragma unroll
      for (int s4 = 0; s4 < 4; ++s4) {
        int d = d0 + ty + 8 * s4;
        nfT[(size_t)d * NFR + k0b + tx] = f2bf(tile[tx][ty + 8 * s4] * iv);
      }
      if (ty == 0) {
        float s2 = 0.f;
#pragma unroll
        for (int w2 = 0; w2 < 8; ++w2) s2 += cred[w2][tx];
        kpart[b2 * D_EMB + d0 + tx] = s2;
      }
      __syncthreads();
    }
    return;
  }

  if (blockIdx.x >= 512) {  // ---------- text row l2norm (eps=0) ----------
    const int row = blockIdx.x - 512;
    const float* x = text + (size_t)row * D_EMB;
    float4 vv[2];
    float ss = 0.f;
#pragma unroll
    for (int i = 0; i < 2; ++i) {
      int idx = t + i * 256;
      if (idx < 288) {
        float4 v = ((const float4*)x)[idx];
        vv[i] = v;
        ss += v.x * v.x + v.y * v.y + v.z * v.z + v.w * v.w;
      }
    }
#pragma unroll
    for (int off = 32; off; off >>= 1) ss += __shfl_down(ss, off);
    if ((t & 63) == 0) wsum2[t >> 6] = ss;
    __syncthreads();
    float inv = 1.f / sqrtf(wsum2[0] + wsum2[1] + wsum2[2] + wsum2[3]);
#pragma unroll
    for (int i = 0; i < 2; ++i) {
      int idx = t + i * 256;
      if (idx < 288) {
        float4 v = vv[i];
        u16 a = f2bf(v.x * inv), b = f2bf(v.y * inv), c = f2bf(v.z * inv), d = f2bf(v.w * inv);
        uint2 pk;
        pk.x = (unsigned)a | ((unsigned)b << 16);
        pk.y = (unsigned)c | ((unsigned)d << 16);
        *(uint2*)(te_n + (size_t)row * D_EMB + idx * 4) = pk;
      }
    }
    return;
  }

  // ---------- local fusion (one clip of 8 frames) ----------
  const int c = blockIdx.x;
  const float* src = fe + (size_t)c * 8 * D_EMB;
  for (int i = t; i < 2304; i += 256) {
    int r = i / 288, qd = i - r * 288;
    float4 v = ((const float4*)(src + r * D_EMB))[qd];
    *(float4*)&clip[r][qd * 4] = v;
  }
  __syncthreads();
  {  // row norms, float4
    int r = t >> 5, l32 = t & 31;
    const float4* cr = (const float4*)&clip[r][0];
    float ss = 0.f;
#pragma unroll
    for (int k = 0; k < 9; ++k) {
      float4 v = cr[l32 + k * 32];
      ss += v.x * v.x + v.y * v.y + v.z * v.z + v.w * v.w;
    }
#pragma unroll
    for (int off = 16; off; off >>= 1) ss += __shfl_xor(ss, off);
    if (l32 == 0) norms[r] = sqrtf(ss) + 1e-6f;
  }
  __syncthreads();
  {  // Gram (symmetric: 36 pairs), float4
    int p = t >> 2, sub = t & 3;
    if (p < 36) {
      int z = p, i = 0;
      while (z >= 8 - i) { z -= 8 - i; ++i; }
      int j = i + z;
      const float4* ci = (const float4*)&clip[i][0];
      const float4* cj = (const float4*)&clip[j][0];
      float s = 0.f;
      for (int k = sub; k < 288; k += 4) {
        float4 a = ci[k], b = cj[k];
        s += a.x * b.x + a.y * b.y + a.z * b.z + a.w * b.w;
      }
      s += __shfl_xor(s, 1);
      s += __shfl_xor(s, 2);
      if (sub == 0) {
        float v = s / (norms[i] * norms[j]);
        sc[i][j] = v;
        sc[j][i] = v;
      }
    }
  }
  __syncthreads();
  const float inv_tls = 1.f / (__expf(tau_lp[0]) * SQRT_D);
  if (t < 64) {
    int i = t >> 3, j = t & 7;
    float v = sc[i][j] * inv_tls;
    float mx = v;
#pragma unroll
    for (int off = 1; off < 8; off <<= 1) mx = fmaxf(mx, __shfl_xor(mx, off));
    float e = __expf(v - mx);
    float s = e;
#pragma unroll
    for (int off = 1; off < 8; off <<= 1) s += __shfl_xor(s, off);
    sc[i][j] = e / s;
  }
  __syncthreads();
  {  // fused output + nf, float4
    int r = t >> 5, l32 = t & 31;
    float w[8];
#pragma unroll
    for (int j = 0; j < 8; ++j) w[j] = sc[r][j];
    const float invn_nf = 1.f / norms[r];
    float4 av[9];
    float rs = 0.f;
#pragma unroll
    for (int kk = 0; kk < 9; ++kk) {
      int d4 = l32 + kk * 32;
      float4 a = {0.f, 0.f, 0.f, 0.f};
#pragma unroll
      for (int j = 0; j < 8; ++j) {
        float4 cj4 = ((const float4*)&clip[j][0])[d4];
        a.x += w[j] * cj4.x;
        a.y += w[j] * cj4.y;
        a.z += w[j] * cj4.z;
        a.w += w[j] * cj4.w;
      }
      av[kk] = a;
      rs += a.x * a.x + a.y * a.y + a.z * a.z + a.w * a.w;
      float4 me = ((const float4*)&clip[r][0])[d4];
      uint2 pk;
      pk.x = (unsigned)f2bf(me.x * invn_nf) | ((unsigned)f2bf(me.y * invn_nf) << 16);
      pk.y = (unsigned)f2bf(me.z * invn_nf) | ((unsigned)f2bf(me.w * invn_nf) << 16);
      *(uint2*)(nf + (size_t)(c * 8 + r) * D_EMB + d4 * 4) = pk;
    }
#pragma unroll
    for (int off = 16; off; off >>= 1) rs += __shfl_xor(rs, off);
    if (l32 == 0) nrm2[r] = rs;
    __syncthreads();
    float invn = 1.f / sqrtf(nrm2[r]);
#pragma unroll
    for (int kk = 0; kk < 9; ++kk) {
      int d4 = l32 + kk * 32;
      float4 a = av[kk];
      uint2 pk;
      pk.x = (unsigned)f2bf(a.x * invn) | ((unsigned)f2bf(a.y * invn) << 16);
      pk.y = (unsigned)f2bf(a.z * invn) | ((unsigned)f2bf(a.w * invn) << 16);
      *(uint2*)(loc_n + (size_t)(c * 8 + r) * D_EMB + d4 * 4) = pk;
    }
  }
}

// ==== scoreA: d0/d1 via MFMA; P1 = .9d0+.05d1, A0 = d0*rn, u = bf16(A0); blocks>=256: colsum ====
__global__ __launch_bounds__(256) void k_scoreA(const u16* __restrict__ te_n,
                                                const u16* __restrict__ nf,
                                                const u16* __restrict__ loc_n,
                                                const float* __restrict__ invr,
                                                const float* __restrict__ kpart,
                                                float* __restrict__ colsum,
                                                float* __restrict__ P1,
                                                float* __restrict__ A0,
                                                u16* __restrict__ ubf) {
  const int tid = threadIdx.x;
  if (blockIdx.x >= 256) {  // colsum reduce (9 blocks x 128 threads)
    if (tid < 128) {
      const int col = (blockIdx.x - 256) * 128 + tid;
      float s = 0.f;
      for (int kb = 0; kb < 128; ++kb) s += kpart[kb * D_EMB + col];
      colsum[col] = s;
    }
    return;
  }
  const int lane = tid & 63;
  const int wave = tid >> 6;
  const int f0 = blockIdx.x * 16;
  const int fr = lane & 15;
  const int k8 = (lane >> 4) * 8;
  const int kbase = wave * 288;
  f32x4 a0 = {}, a1 = {};
  const u16* teP = te_n + fr * D_EMB + kbase + k8;
  const u16* nfP = nf + (size_t)(f0 + fr) * D_EMB + kbase + k8;
  const u16* lcP = loc_n + (size_t)(f0 + fr) * D_EMB + kbase + k8;
#pragma unroll
  for (int kc = 0; kc < 9; ++kc) {
    bf16x8 aTe = *(const bf16x8*)(teP + kc * 32);
    bf16x8 bNf = *(const bf16x8*)(nfP + kc * 32);
    bf16x8 bLc = *(const bf16x8*)(lcP + kc * 32);
    a0 = __builtin_amdgcn_mfma_f32_16x16x32_bf16(aTe, bNf, a0, 0, 0, 0);
    a1 = __builtin_amdgcn_mfma_f32_16x16x32_bf16(aTe, bLc, a1, 0, 0, 0);
  }
  __shared__ float red[2][4][256];
#pragma unroll
  for (int r = 0; r < 4; ++r) {
    red[0][wave][lane * 4 + r] = a0[r];
    red[1][wave][lane * 4 + r] = a1[r];
  }
  __syncthreads();
  if (wave == 0) {
    const int f = f0 + fr;
    const float rn = 1.f / invr[f];
#pragma unroll
    for (int r = 0; r < 4; ++r) {
      int li = lane * 4 + r;
      float d0 = red[0][0][li] + red[0][1][li] + red[0][2][li] + red[0][3][li];
      float d1 = red[1][0][li] + red[1][1][li] + red[1][2][li] + red[1][3][li];
      int q = (lane >> 4) * 4 + r;
      P1[(size_t)q * NFR + f] = 0.9f * d0 + 0.05f * d1;
      float a = d0 * rn;
      A0[(size_t)q * NFR + f] = a;
      ubf[(size_t)q * NFR + f] = f2bf(a);
    }
  }
}

// ---- tg partials: tgpart[p][q][d] = (nfT . u^T) split-K 16; p = by*4+wave (64 partials) ----
__global__ __launch_bounds__(256) void k_tg(const u16* __restrict__ nfT,
                                            const u16* __restrict__ ubf,
                                            float* __restrict__ tgpart) {
  const int tid = threadIdx.x;
  const int lane = tid & 63;
  const int wave = tid >> 6;
  const int d0 = blockIdx.x * 128;
  const int kb = blockIdx.y * 256 + wave * 64;
  const int fr = lane & 15;
  const int k8 = (lane >> 4) * 8;
  f32x4 acc[8] = {};
#pragma unroll
  for (int ks = 0; ks < 2; ++ks) {
    int kk = kb + ks * 32;
    bf16x8 b = *(const bf16x8*)&ubf[(size_t)fr * NFR + kk + k8];
#pragma unroll
    for (int m = 0; m < 8; ++m) {
      bf16x8 a = *(const bf16x8*)&nfT[(size_t)(d0 + m * 16 + fr) * NFR + kk + k8];
      acc[m] = __builtin_amdgcn_mfma_f32_16x16x32_bf16(a, b, acc[m], 0, 0, 0);
    }
  }
  float* dst = tgpart + (size_t)(blockIdx.y * 4 + wave) * 16 * D_EMB;
  const int q = fr;
#pragma unroll
  for (int m = 0; m < 8; ++m) {
#pragma unroll
    for (int r = 0; r < 4; ++r) {
      int d = d0 + m * 16 + (lane >> 4) * 4 + r;
      dst[(size_t)q * D_EMB + d] = acc[m][r];
    }
  }
}

// ---- reduce 64 tg partials -> tg bf16 [16][1152]; block 72 computes tec[17] ----
__global__ __launch_bounds__(256) void k_tgred(const float* __restrict__ tgpart,
                                               const u16* __restrict__ te_n,
                                               const float* __restrict__ colsum,
                                               u16* __restrict__ tg,
                                               float* __restrict__ tec) {
  const int t = threadIdx.x;
  if (blockIdx.x < 72) {
    const int idx = blockIdx.x * 256 + t;
    float s = 0.f;
#pragma unroll
    for (int p = 0; p < 64; ++p) s += tgpart[(size_t)p * 18432 + idx];
    tg[idx] = f2bf(s);
  } else {
    if (t < 136) {
      const int v = t >> 3, s8 = t & 7;
      float s = 0.f;
      for (int i = s8; i < D_EMB; i += 8) {
        float a = (v < 16) ? bf2f(te_n[v * D_EMB + i]) : colsum[i];
        s += a * colsum[i];
      }
      s += __shfl_xor(s, 1);
      s += __shfl_xor(s, 2);
      s += __shfl_xor(s, 4);
      if (s8 == 0) tec[v] = s;
    }
  }
}

// ---- scoreB: dtg = tg.nf via MFMA; fuse with P1/A0/tec; max over q -> logits ----
__global__ __launch_bounds__(256) void k_scoreB(const u16* __restrict__ tg,
                                                const u16* __restrict__ nf,
                                                const float* __restrict__ P1,
                                                const float* __restrict__ A0,
                                                const float* __restrict__ tec,
                                                float* __restrict__ logits,
                                                const float* __restrict__ tau_gp,
                                                const float* __restrict__ lsp,
                                                const float* __restrict__ lbp) {
  const int tid = threadIdx.x;
  const int lane = tid & 63;
  const int wave = tid >> 6;
  const int f0 = blockIdx.x * 16;
  const int fr = lane & 15;
  const int k8 = (lane >> 4) * 8;
  const int kbase = wave * 288;
  f32x4 a2 = {};
  const u16* tgP = tg + fr * D_EMB + kbase + k8;
  const u16* nfP = nf + (size_t)(f0 + fr) * D_EMB + kbase + k8;
#pragma unroll
  for (int kc = 0; kc < 9; ++kc) {
    bf16x8 aTg = *(const bf16x8*)(tgP + kc * 32);
    bf16x8 bNf = *(const bf16x8*)(nfP + kc * 32);
    a2 = __builtin_amdgcn_mfma_f32_16x16x32_bf16(aTg, bNf, a2, 0, 0, 0);
  }
  __shared__ float red[4][256];
#pragma unroll
  for (int r = 0; r < 4; ++r) red[wave][lane * 4 + r] = a2[r];
  __syncthreads();
  if (wave == 0) {
    const float inv = 1.f / (__expf(tau_gp[0]) * SQRT_D);
    const float delta = inv * inv * (0.5f + inv * (1.f / 6.f) + inv * inv * (1.f / 24.f));
    const float rsq = rsqrtf(tec[16]);
    const float els = __expf(lsp[0]);
    const float bias = lbp[0];
    const int f = f0 + fr;
    float mx = -1e30f;
#pragma unroll
    for (int r = 0; r < 4; ++r) {
      int li = lane * 4 + r;
      float dtg = red[0][li] + red[1][li] + red[2][li] + red[3][li];
      int q = (lane >> 4) * 4 + r;
      float glob = (tec[q] + inv * dtg + delta * A0[(size_t)q * NFR + f]) * rsq;
      float fused = els * (P1[(size_t)q * NFR + f] + 0.05f * glob) + bias;
      mx = fmaxf(mx, fused);
    }
    mx = fmaxf(mx, __shfl_xor(mx, 16));
    mx = fmaxf(mx, __shfl_xor(mx, 32));
    if (lane < 16) logits[f0 + lane] = mx;
  }
}

// ---------------- softmax-pool per clip + loss ----------------
__global__ __launch_bounds__(512) void k_final(const float* __restrict__ logits,
                                               const float* __restrict__ labels,
                                               float* __restrict__ out) {
  const int t = threadIdx.x;
  float x[8];
  float m = -1e30f;
#pragma unroll
  for (int j = 0; j < 8; ++j) { x[j] = logits[t * 8 + j]; m = fmaxf(m, x[j]); }
  float se = 0, swx = 0;
#pragma unroll
  for (int j = 0; j < 8; ++j) { float e = __expf(x[j] - m); se += e; swx += e * x[j]; }
  float pooled = swx / se;
  out[1 + t] = pooled;
  float lab = labels[t * 8];
  __shared__ float red[8];
  float v = lab;
#pragma unroll
  for (int off = 32; off; off >>= 1) v += __shfl_down(v, off);
  if ((t & 63) == 0) red[t >> 6] = v;
  __syncthreads();
  float total = 0;
#pragma unroll
  for (int w = 0; w < 8; ++w) total += red[w];
  float mean = total * (1.f / 512.f);
  float wgt = pooled * (lab - mean);
  float lsg = (wgt >= 0.f) ? -log1pf(__expf(-wgt)) : (wgt - log1pf(__expf(wgt)));
  __syncthreads();
  float v2 = lsg;
#pragma unroll
  for (int off = 32; off; off >>= 1) v2 += __shfl_down(v2, off);
  if ((t & 63) == 0) red[t >> 6] = v2;
  __syncthreads();
  if (t == 0) {
    float tl = 0;
#pragma unroll
    for (int w = 0; w < 8; ++w) tl += red[w];
    out[0] = -tl;
  }
}

extern "C" void kernel_launch(void* const* d_in, const int* in_sizes, int n_in,
                              void* d_out, int out_size, void* d_ws, size_t ws_size,
                              hipStream_t stream) {
  const float* fe = (const float*)d_in[0];
  const float* text = (const float*)d_in[1];
  const float* labels = (const float*)d_in[2];
  const float* tau_lp = (const float*)d_in[3];
  const float* tau_gp = (const float*)d_in[4];
  const float* lsp = (const float*)d_in[5];
  const float* lbp = (const float*)d_in[6];
  float* out = (float*)d_out;
  char* ws = (char*)d_ws;

  // ws layout (bytes), 256-aligned, total ~34.4 MB:
  u16* nf = (u16*)(ws + 0);                 // 4096x1152 bf16
  u16* nfT = (u16*)(ws + 9437184);          // 1152x4096 bf16
  u16* loc_n = (u16*)(ws + 18874368);       // 4096x1152 bf16
  u16* te_n = (u16*)(ws + 28311552);        // 16x1152 bf16
  float* invr = (float*)(ws + 28348416);    // 4096 f32
  float* colsum = (float*)(ws + 28364800);  // 1152 f32
  float* kpart = (float*)(ws + 28369408);   // 128x1152 f32
  float* logits = (float*)(ws + 28959232);  // 4096 f32
  float* tec = (float*)(ws + 28975616);     // 17 f32
  float* P1 = (float*)(ws + 28975872);      // 16x4096 f32
  float* A0 = (float*)(ws + 29238016);      // 16x4096 f32
  u16* ubf = (u16*)(ws + 29500160);         // 16x4096 bf16
  float* tgpart = (float*)(ws + 29631232);  // 64x16x1152 f32
  u16* tg = (u16*)(ws + 34349824);          // 16x1152 bf16

  hipLaunchKernelGGL(k_prep, dim3(656), dim3(256), 0, stream, fe, text, loc_n, nf, te_n, nfT,
                     invr, kpart, tau_lp);
  hipLaunchKernelGGL(k_scoreA, dim3(265), dim3(256), 0, stream, te_n, nf, loc_n, invr, kpart,
                     colsum, P1, A0, ubf);
  hipLaunchKernelGGL(k_tg, dim3(9, 16), dim3(256), 0, stream, nfT, ubf, tgpart);
  hipLaunchKernelGGL(k_tgred, dim3(73), dim3(256), 0, stream, tgpart, te_n, colsum, tg, tec);
  hipLaunchKernelGGL(k_scoreB, dim3(256), dim3(256), 0, stream, tg, nf, P1, A0, tec, logits,
                     tau_gp, lsp, lbp);
  hipLaunchKernelGGL(k_final, dim3(1), dim3(512), 0, stream, logits, labels, out);
}